// Round 3
// baseline (202.601 us; speedup 1.0000x reference)
//
#include <hip/hip_runtime.h>
#include <cstdint>

// B=4, S=512, D=512, H=8, TM=20, DH=64
// out layout: out[1048576] | attn[8388608] | reg[1] | T_i[2048]  (all float)

typedef __attribute__((ext_vector_type(8))) _Float16 f16x8;
typedef __attribute__((ext_vector_type(4))) float f32x4;

__device__ __forceinline__ float sep_mad(float a, float b, float c) {
    // separate mul+add rounding (matches numpy), blocks FMA contraction:
    // spike threshold is discontinuous.
    float t = a * b;
    asm volatile("" : "+v"(t));
    return t + c;
}

union HU4 { _Float16 h[4]; ushort4 u; };
union HU8 { _Float16 h[8]; uint4 u; };

// ---------------- Kernel 0: split fp32 -> fp16 hi/lo (x, Wq, Wk, Wv) + Wo fp16 ----------------
__global__ __launch_bounds__(256) void k_split(
    const float* __restrict__ x,
    const float* __restrict__ Wq, const float* __restrict__ Wk,
    const float* __restrict__ Wv, const float* __restrict__ Wo,
    _Float16* __restrict__ xh, _Float16* __restrict__ xl,
    _Float16* __restrict__ Wh, _Float16* __restrict__ Wl,
    _Float16* __restrict__ Woh)
{
    const int t = blockIdx.x * 256 + threadIdx.x;   // one float4 per thread
    float4 v;
    HU4 hi, lo;
    if (t < 262144) {
        v = ((const float4*)x)[t];
        hi.h[0] = (_Float16)v.x; lo.h[0] = (_Float16)(v.x - (float)hi.h[0]);
        hi.h[1] = (_Float16)v.y; lo.h[1] = (_Float16)(v.y - (float)hi.h[1]);
        hi.h[2] = (_Float16)v.z; lo.h[2] = (_Float16)(v.z - (float)hi.h[2]);
        hi.h[3] = (_Float16)v.w; lo.h[3] = (_Float16)(v.w - (float)hi.h[3]);
        ((ushort4*)xh)[t] = hi.u;
        ((ushort4*)xl)[t] = lo.u;
    } else {
        const int t2 = t - 262144;
        const int sel = t2 >> 16;          // 0..3 -> Wq, Wk, Wv, Wo
        const int o = t2 & 65535;
        const float* src = (sel == 0) ? Wq : ((sel == 1) ? Wk : ((sel == 2) ? Wv : Wo));
        v = ((const float4*)src)[o];
        hi.h[0] = (_Float16)v.x; lo.h[0] = (_Float16)(v.x - (float)hi.h[0]);
        hi.h[1] = (_Float16)v.y; lo.h[1] = (_Float16)(v.y - (float)hi.h[1]);
        hi.h[2] = (_Float16)v.z; lo.h[2] = (_Float16)(v.z - (float)hi.h[2]);
        hi.h[3] = (_Float16)v.w; lo.h[3] = (_Float16)(v.w - (float)hi.h[3]);
        if (sel < 3) {
            ((ushort4*)(Wh + sel * 262144))[o] = hi.u;
            ((ushort4*)(Wl + sel * 262144))[o] = lo.u;
        } else {
            ((ushort4*)Woh)[o] = hi.u;
        }
    }
}

// ---------------- Kernel 1: fused gate MLPs -> T_i ----------------
__global__ __launch_bounds__(256) void k_gates(
    const float* __restrict__ x,
    const float* __restrict__ gw1, const float* __restrict__ gb1,
    const float* __restrict__ gw2, const float* __restrict__ gb2,
    const float* __restrict__ gw3, const float* __restrict__ gb3,
    const float* __restrict__ cw1, const float* __restrict__ cb1,
    const float* __restrict__ cw2, const float* __restrict__ cb2,
    int* __restrict__ Ti, float* __restrict__ ti_out)
{
    __shared__ float xs[8][516];
    __shared__ float h1s[8][100];
    __shared__ float h2s[8][36];
    const int tok0 = blockIdx.x * 8;
    const int tid = threadIdx.x;

    for (int i = tid; i < 1024; i += 256) {
        int tok = i >> 7, c4 = i & 127;
        *(float4*)&xs[tok][c4 * 4] = ((const float4*)(x + (tok0 + tok) * 512))[c4];
    }
    __syncthreads();

    {
        const int o = tid & 127;
        const int tg = tid >> 7;
        const int oc = (o < 96) ? o : 95;
        const float4* wrow = (const float4*)((oc < 64) ? (gw1 + oc * 512) : (cw1 + (oc - 64) * 512));
        const float bias = (oc < 64) ? gb1[oc] : cb1[oc - 64];
        float acc[4];
#pragma unroll
        for (int t = 0; t < 4; t++) acc[t] = bias;
        for (int k4 = 0; k4 < 128; k4++) {
            float4 w4 = wrow[k4];
#pragma unroll
            for (int t = 0; t < 4; t++) {
                float4 x4 = *(const float4*)&xs[tg * 4 + t][k4 * 4];
                acc[t] = fmaf(w4.x, x4.x, acc[t]); acc[t] = fmaf(w4.y, x4.y, acc[t]);
                acc[t] = fmaf(w4.z, x4.z, acc[t]); acc[t] = fmaf(w4.w, x4.w, acc[t]);
            }
        }
        if (o < 96) {
#pragma unroll
            for (int t = 0; t < 4; t++) h1s[tg * 4 + t][o] = fmaxf(acc[t], 0.f);
        }
    }
    __syncthreads();
    {
        const int tok = tid >> 5, o2 = tid & 31;
        const float* w2 = gw2 + o2 * 64;
        float a = gb2[o2];
        for (int k = 0; k < 64; k++) a = fmaf(w2[k], h1s[tok][k], a);
        h2s[tok][o2] = fmaxf(a, 0.f);
    }
    __syncthreads();
    if (tid < 8) {
        const int tok = tid;
        float gg = gb3[0], cc = cb2[0];
        for (int k = 0; k < 32; k++) {
            gg = fmaf(gw3[k], h2s[tok][k], gg);
            cc = fmaf(cw2[k], h1s[tok][64 + k], cc);
        }
        float g = 1.f / (1.f + expf(-gg));
        float c = 1.f / (1.f + expf(-cc));
        float p1 = 0.7f * g, p2 = 0.3f * c;
        asm volatile("" : "+v"(p1), "+v"(p2));
        float comb = p1 + p2;
        float tf = ceilf(comb * 20.0f);
        tf = fminf(fmaxf(tf, 1.f), 20.f);
        Ti[tok0 + tok] = (int)tf;
        ti_out[tok0 + tok] = tf;
    }
}

// ---------------- Kernel 2: MFMA GEMM  Y = X @ W^T (+bias) ----------------
// NP=3: fp16x3 (hi/lo) high-precision; NP=1: plain fp16.
// M=2048, N=512, K=512. Tile BM=BN=128, BK=32. 256 thr = 4 waves, wave-tile 64x64.
// LDS layout [kc][row][8halves]: frag read = one b128 per lane, conflict-free.
// MFMA 16x16x32_f16: A lane: row=l&15, k=(l>>4)*8+j ; C/D: col=l&15, row=(l>>4)*4+reg.
template<int NP>
__global__ __launch_bounds__(256) void k_gemm(
    const _Float16* __restrict__ Ah, const _Float16* __restrict__ Al,
    const _Float16* __restrict__ Bh0, const _Float16* __restrict__ Bl0,
    const float* __restrict__ bias,
    float* __restrict__ Y0)
{
    __shared__ _Float16 AsH[4][128][8];
    __shared__ _Float16 BsH[4][128][8];
    __shared__ _Float16 AsL[(NP == 3) ? 4 : 1][128][8];
    __shared__ _Float16 BsL[(NP == 3) ? 4 : 1][128][8];

    const _Float16* Bh = Bh0 + blockIdx.z * 262144;
    const _Float16* Bl = (NP == 3) ? (Bl0 + blockIdx.z * 262144) : Bl0;
    float* Y = Y0 + blockIdx.z * 1048576;
    const int bn = blockIdx.x * 128, bm = blockIdx.y * 128;
    const int tid = threadIdx.x, w = tid >> 6, l = tid & 63;
    const int mB = (w & 1) * 64, nB = (w >> 1) * 64;
    const int sr = tid & 127, si = tid >> 7;   // staging row, kc-pair
    const int fr = l & 15, fk = l >> 4;

    f32x4 acc[4][4] = {};

    uint4 pAh[2], pBh[2], pAl[2], pBl[2];
#pragma unroll
    for (int i = 0; i < 2; i++) {
        const int kc = si * 2 + i;
        pAh[i] = *(const uint4*)(Ah + (bm + sr) * 512 + kc * 8);
        pBh[i] = *(const uint4*)(Bh + (bn + sr) * 512 + kc * 8);
        if constexpr (NP == 3) {
            pAl[i] = *(const uint4*)(Al + (bm + sr) * 512 + kc * 8);
            pBl[i] = *(const uint4*)(Bl + (bn + sr) * 512 + kc * 8);
        }
    }

    for (int k0 = 0; k0 < 512; k0 += 32) {
        __syncthreads();
#pragma unroll
        for (int i = 0; i < 2; i++) {
            const int kc = si * 2 + i;
            *(uint4*)&AsH[kc][sr][0] = pAh[i];
            *(uint4*)&BsH[kc][sr][0] = pBh[i];
            if constexpr (NP == 3) {
                *(uint4*)&AsL[kc][sr][0] = pAl[i];
                *(uint4*)&BsL[kc][sr][0] = pBl[i];
            }
        }
        __syncthreads();
        const int kn = (k0 + 32) & 511;   // wraps harmlessly on last iter
#pragma unroll
        for (int i = 0; i < 2; i++) {
            const int kc = si * 2 + i;
            pAh[i] = *(const uint4*)(Ah + (bm + sr) * 512 + kn + kc * 8);
            pBh[i] = *(const uint4*)(Bh + (bn + sr) * 512 + kn + kc * 8);
            if constexpr (NP == 3) {
                pAl[i] = *(const uint4*)(Al + (bm + sr) * 512 + kn + kc * 8);
                pBl[i] = *(const uint4*)(Bl + (bn + sr) * 512 + kn + kc * 8);
            }
        }

        f16x8 ah[4], al[4];
#pragma unroll
        for (int mt = 0; mt < 4; mt++) {
            ah[mt] = *(const f16x8*)&AsH[fk][mB + mt * 16 + fr][0];
            if constexpr (NP == 3) al[mt] = *(const f16x8*)&AsL[fk][mB + mt * 16 + fr][0];
        }
#pragma unroll
        for (int nt = 0; nt < 4; nt++) {
            f16x8 bh = *(const f16x8*)&BsH[fk][nB + nt * 16 + fr][0];
            if constexpr (NP == 3) {
                f16x8 bl = *(const f16x8*)&BsL[fk][nB + nt * 16 + fr][0];
#pragma unroll
                for (int mt = 0; mt < 4; mt++) {
                    acc[mt][nt] = __builtin_amdgcn_mfma_f32_16x16x32_f16(ah[mt], bh, acc[mt][nt], 0, 0, 0);
                    acc[mt][nt] = __builtin_amdgcn_mfma_f32_16x16x32_f16(ah[mt], bl, acc[mt][nt], 0, 0, 0);
                    acc[mt][nt] = __builtin_amdgcn_mfma_f32_16x16x32_f16(al[mt], bh, acc[mt][nt], 0, 0, 0);
                }
            } else {
#pragma unroll
                for (int mt = 0; mt < 4; mt++) {
                    acc[mt][nt] = __builtin_amdgcn_mfma_f32_16x16x32_f16(ah[mt], bh, acc[mt][nt], 0, 0, 0);
                }
            }
        }
    }

#pragma unroll
    for (int mt = 0; mt < 4; mt++) {
#pragma unroll
        for (int nt = 0; nt < 4; nt++) {
            const int j = bn + nB + nt * 16 + fr;
            float badd = (NP == 1) ? bias[j] : 0.f;
#pragma unroll
            for (int rr = 0; rr < 4; rr++) {
                const int i = bm + mB + mt * 16 + fk * 4 + rr;
                Y[i * 512 + j] = acc[mt][nt][rr] + badd;
            }
        }
    }
}

// ---------------- Kernel 3: LIF + ballot bit-pack + v spike counts ----------------
__global__ __launch_bounds__(256) void k_lif(
    const float* __restrict__ qkv,           // [3][2048][512]
    const int* __restrict__ Ti,
    const float* __restrict__ pAlpha, const float* __restrict__ pBeta,
    unsigned long long* __restrict__ qbits,  // [(b*8+h)*20 + t]*512 + s
    unsigned long long* __restrict__ kbits,
    _Float16* __restrict__ vmean)            // [tok*512 + h*64 + d] fp16
{
    const int wid = threadIdx.x >> 6, lane = threadIdx.x & 63;
    const int flat = blockIdx.x * 4 + wid;   // (b,s,h)
    const int tok = flat >> 3, h = flat & 7;
    const int b = tok >> 9, s = tok & 511;
    const float alpha = pAlpha[0], beta = pBeta[0];
    const int T = Ti[tok];
    const int off = tok * 512 + h * 64 + lane;
    const float xq = qkv[off];
    const float xk = qkv[off + 1048576];
    const float xv = qkv[off + 2097152];
    float iq = 0.f, vq = 0.f, ik = 0.f, vk = 0.f, iv = 0.f, vv = 0.f;
    int cnt = 0;
    const int base = ((b * 8 + h) * 20) * 512 + s;
#pragma unroll
    for (int t = 0; t < 20; t++) {
        iq = sep_mad(alpha, iq, xq); vq = sep_mad(beta, vq, iq);
        bool sq = vq >= 1.0f; vq = sq ? 0.f : vq;
        ik = sep_mad(alpha, ik, xk); vk = sep_mad(beta, vk, ik);
        bool sk = vk >= 1.0f; vk = sk ? 0.f : vk;
        iv = sep_mad(alpha, iv, xv); vv = sep_mad(beta, vv, iv);
        bool sv = vv >= 1.0f; vv = sv ? 0.f : vv;
        bool act = t < T;
        unsigned long long mq = __ballot(sq && act);
        unsigned long long mk = __ballot(sk && act);
        if (lane == 0) {
            qbits[base + t * 512] = mq;
            kbits[base + t * 512] = mk;
        }
        cnt += (sv && act) ? 1 : 0;
    }
    vmean[off] = (_Float16)((float)cnt / 20.0f);
}

// ---------------- Kernel 4: transpose v_mean [tok][h*64+d] -> vmT [bh][d][s] (fp16) ----------------
__global__ __launch_bounds__(256) void k_pack(
    const _Float16* __restrict__ vmean, _Float16* __restrict__ vmT)
{
    __shared__ _Float16 T[64][72];   // 72-pad: rows 144B (16B-aligned)
    const int s0 = blockIdx.x * 64;
    const int bh = blockIdx.y;
    const int b = bh >> 3, h = bh & 7;
    const int t = threadIdx.x;
    const int si = t >> 2;
#pragma unroll
    for (int it = 0; it < 2; it++) {
        const int dv = (t & 3) + it * 4;
        uint4 v = *(const uint4*)(vmean + (b * 512 + s0 + si) * 512 + h * 64 + dv * 8);
        *(uint4*)&T[si][dv * 8] = v;
    }
    __syncthreads();
    const int sv = t & 63;
#pragma unroll
    for (int it = 0; it < 16; it++) {
        const int d = it * 4 + (t >> 6);
        vmT[(bh * 64 + d) * 512 + s0 + sv] = T[sv][d];
    }
}

// ---------------- Kernel 5: popcount scores + softmax -> attn (+fused reg) ----------------
__global__ __launch_bounds__(256) void k_scores(
    const unsigned long long* __restrict__ qbits,
    const unsigned long long* __restrict__ kbits,
    float* __restrict__ attn,
    const int* __restrict__ Ti, float* __restrict__ regp)
{
    const int bh = blockIdx.x >> 5;            // 0..31
    const int i0 = (blockIdx.x & 31) * 16;
    const int base = bh * 20 * 512;
    __shared__ unsigned long long qs[20][16];
    __shared__ float sc[16][512];
    const int tid = threadIdx.x;
    for (int idx = tid; idx < 320; idx += 256) {
        int t = idx >> 4, r = idx & 15;
        qs[t][r] = qbits[base + t * 512 + i0 + r];
    }
    __syncthreads();

    {
        const unsigned long long* kbp = kbits + base + tid;
        int acc0[16] = {}, acc1[16] = {};
#pragma unroll
        for (int tc = 0; tc < 4; tc++) {
            unsigned long long kv0[5], kv1[5];
#pragma unroll
            for (int t = 0; t < 5; t++) {
                kv0[t] = kbp[(tc * 5 + t) * 512];
                kv1[t] = kbp[(tc * 5 + t) * 512 + 256];
            }
#pragma unroll
            for (int r = 0; r < 16; r++) {
#pragma unroll
                for (int t = 0; t < 5; t++) {
                    unsigned long long qv = qs[tc * 5 + t][r];
                    acc0[r] += __popcll(qv & kv0[t]);
                    acc1[r] += __popcll(qv & kv1[t]);
                }
            }
        }
#pragma unroll
        for (int r = 0; r < 16; r++) {
            sc[r][tid] = (float)acc0[r] * 0.125f;
            sc[r][tid + 256] = (float)acc1[r] * 0.125f;
        }
    }
    __syncthreads();

    const int wid = tid >> 6, lane = tid & 63;
#pragma unroll
    for (int rr = 0; rr < 4; rr++) {
        const int r = wid * 4 + rr;
        float vals[8];
        float m = -1e30f;
#pragma unroll
        for (int k = 0; k < 8; k++) { vals[k] = sc[r][lane + 64 * k]; m = fmaxf(m, vals[k]); }
#pragma unroll
        for (int off = 32; off; off >>= 1) m = fmaxf(m, __shfl_xor(m, off));
        float sum = 0.f;
#pragma unroll
        for (int k = 0; k < 8; k++) { vals[k] = expf(vals[k] - m); sum += vals[k]; }
#pragma unroll
        for (int off = 32; off; off >>= 1) sum += __shfl_xor(sum, off);
        float* arow = attn + ((long)bh * 512 + (i0 + r)) * 512;
#pragma unroll
        for (int k = 0; k < 8; k++) arow[lane + 64 * k] = vals[k] / sum;
    }

    if (blockIdx.x == 0 && tid < 64) {
        int s = 0;
        for (int k = tid; k < 2048; k += 64) s += Ti[k];
#pragma unroll
        for (int off = 32; off; off >>= 1) s += __shfl_xor(s, off);
        if (tid == 0) regp[0] = 1e-3f * ((float)s / 2048.0f);
    }
}

// ---------------- Kernel 6: MFMA AV  hout = attn @ v_mean  (per b,h; fp16) ----------------
// BM=128 (i), BN=64 (d), BK=32 (j), K=512. grid (4, 32). Wave-tile 64x32.
__global__ __launch_bounds__(256) void k_av(
    const float* __restrict__ attn,
    const _Float16* __restrict__ vmT,   // [bh][d][s]
    _Float16* __restrict__ hout)        // [tok][h*64+d] fp16
{
    __shared__ _Float16 Aa[4][128][8];
    __shared__ _Float16 Bb[4][64][8];
    const int i0 = blockIdx.x * 128;
    const int bh = blockIdx.y;
    const int b = bh >> 3, h = bh & 7;
    const int tid = threadIdx.x, w = tid >> 6, l = tid & 63;
    const int mB = (w & 1) * 64, nB = (w >> 1) * 32;
    const int sr = tid & 127, si = tid >> 7;
    const int br = tid & 63, bk = tid >> 6;
    const int fr = l & 15, fk = l >> 4;
    const float* abase = attn + ((long)bh * 512 + i0) * 512;
    const _Float16* bbase = vmT + bh * 64 * 512;

    f32x4 acc[4][2] = {};

    float4 pa[2][2];
    uint4 pb;
#pragma unroll
    for (int i = 0; i < 2; i++) {
        const int kc = si * 2 + i;
        pa[i][0] = *(const float4*)(abase + sr * 512 + kc * 8);
        pa[i][1] = *(const float4*)(abase + sr * 512 + kc * 8 + 4);
    }
    pb = *(const uint4*)(bbase + br * 512 + bk * 8);

    for (int k0 = 0; k0 < 512; k0 += 32) {
        __syncthreads();
#pragma unroll
        for (int i = 0; i < 2; i++) {
            const int kc = si * 2 + i;
            HU8 z;
            z.h[0] = (_Float16)pa[i][0].x; z.h[1] = (_Float16)pa[i][0].y;
            z.h[2] = (_Float16)pa[i][0].z; z.h[3] = (_Float16)pa[i][0].w;
            z.h[4] = (_Float16)pa[i][1].x; z.h[5] = (_Float16)pa[i][1].y;
            z.h[6] = (_Float16)pa[i][1].z; z.h[7] = (_Float16)pa[i][1].w;
            *(uint4*)&Aa[kc][sr][0] = z.u;
        }
        *(uint4*)&Bb[bk][br][0] = pb;
        __syncthreads();
        const int kn = (k0 + 32) & 511;
#pragma unroll
        for (int i = 0; i < 2; i++) {
            const int kc = si * 2 + i;
            pa[i][0] = *(const float4*)(abase + sr * 512 + kn + kc * 8);
            pa[i][1] = *(const float4*)(abase + sr * 512 + kn + kc * 8 + 4);
        }
        pb = *(const uint4*)(bbase + br * 512 + kn + bk * 8);

        f16x8 ah[4];
#pragma unroll
        for (int mt = 0; mt < 4; mt++)
            ah[mt] = *(const f16x8*)&Aa[fk][mB + mt * 16 + fr][0];
#pragma unroll
        for (int nt = 0; nt < 2; nt++) {
            f16x8 bv = *(const f16x8*)&Bb[fk][nB + nt * 16 + fr][0];
#pragma unroll
            for (int mt = 0; mt < 4; mt++)
                acc[mt][nt] = __builtin_amdgcn_mfma_f32_16x16x32_f16(ah[mt], bv, acc[mt][nt], 0, 0, 0);
        }
    }

#pragma unroll
    for (int mt = 0; mt < 4; mt++) {
#pragma unroll
        for (int nt = 0; nt < 2; nt++) {
            const int d = nB + nt * 16 + fr;
#pragma unroll
            for (int rr = 0; rr < 4; rr++) {
                const int i = i0 + mB + mt * 16 + fk * 4 + rr;
                hout[(b * 512 + i) * 512 + h * 64 + d] = (_Float16)acc[mt][nt][rr];
            }
        }
    }
}

extern "C" void kernel_launch(void* const* d_in, const int* in_sizes, int n_in,
                              void* d_out, int out_size, void* d_ws, size_t ws_size,
                              hipStream_t stream)
{
    const float* x    = (const float*)d_in[0];
    const float* Wq   = (const float*)d_in[1];
    const float* Wk   = (const float*)d_in[2];
    const float* Wv   = (const float*)d_in[3];
    const float* Wo   = (const float*)d_in[4];
    const float* bo   = (const float*)d_in[5];
    const float* gw1  = (const float*)d_in[6];
    const float* gb1  = (const float*)d_in[7];
    const float* gw2  = (const float*)d_in[8];
    const float* gb2  = (const float*)d_in[9];
    const float* gw3  = (const float*)d_in[10];
    const float* gb3  = (const float*)d_in[11];
    const float* cw1  = (const float*)d_in[12];
    const float* cb1  = (const float*)d_in[13];
    const float* cw2  = (const float*)d_in[14];
    const float* cb2  = (const float*)d_in[15];
    const float* alpha = (const float*)d_in[16];
    const float* beta  = (const float*)d_in[17];

    float* out   = (float*)d_out;                 // [2048*512]
    float* attn  = out + 1048576;                 // [32][512][512]
    float* regp  = out + 1048576 + 8388608;
    float* tiout = regp + 1;

    // workspace layout (bytes); dead-region aliasing keeps total at 21.5 MiB:
    //   qkv fp32 [0, 12582912)  -- after k_lif the region is dead:
    //       vmT    at 0         (2 MiB)
    //       hout_h at 2097152   (2 MiB)
    //   vmean_h 12582912 (2 MiB) | Ti 14680064 | xh 14688256 | xl 16785408
    //   Wh 18882560 | Wl 20455424 | Wo_h 22028288 .. 22552576
    //   qb aliases [xh..] (written by k_lif, after gemm read xh/xl)
    //   kb aliases [xl-end..Wh) likewise
    char* ws = (char*)d_ws;
    float*    qkv    = (float*)ws;
    _Float16* vmT    = (_Float16*)ws;
    _Float16* hout_h = (_Float16*)(ws + 2097152);
    _Float16* vmean_h= (_Float16*)(ws + 12582912);
    int*      Ti     = (int*)(ws + 14680064);
    _Float16* xh     = (_Float16*)(ws + 14688256);
    _Float16* xl     = (_Float16*)(ws + 16785408);
    _Float16* Wh     = (_Float16*)(ws + 18882560);
    _Float16* Wl     = (_Float16*)(ws + 20455424);
    _Float16* Woh    = (_Float16*)(ws + 22028288);
    unsigned long long* qb = (unsigned long long*)(ws + 14688256);
    unsigned long long* kb = (unsigned long long*)(ws + 17309696);

    k_split<<<2048, 256, 0, stream>>>(x, Wq, Wk, Wv, Wo, xh, xl, Wh, Wl, Woh);
    k_gates<<<256, 256, 0, stream>>>(x, gw1, gb1, gw2, gb2, gw3, gb3,
                                     cw1, cb1, cw2, cb2, Ti, tiout);
    k_gemm<3><<<dim3(4, 16, 3), 256, 0, stream>>>(xh, xl, Wh, Wl, nullptr, qkv);
    k_lif<<<4096, 256, 0, stream>>>(qkv, Ti, alpha, beta, qb, kb, vmean_h);
    k_pack<<<dim3(8, 32), 256, 0, stream>>>(vmean_h, vmT);
    k_scores<<<1024, 256, 0, stream>>>(qb, kb, attn, Ti, regp);
    k_av<<<dim3(4, 32), 256, 0, stream>>>(attn, vmT, hout_h);
    k_gemm<1><<<dim3(4, 16, 1), 256, 0, stream>>>(hout_h, nullptr, Woh, nullptr, bo, out);
}

// Round 4
// 132.299 us; speedup vs baseline: 1.5314x; 1.5314x over previous
//
#include <hip/hip_runtime.h>
#include <cstdint>

// B=4, S=512, D=512, H=8, TM=20, DH=64
// out layout: out[1048576] | attn[8388608] | reg[1] | T_i[2048]  (all float)

typedef __attribute__((ext_vector_type(8))) _Float16 f16x8;
typedef __attribute__((ext_vector_type(4))) float f32x4;

__device__ __forceinline__ float sep_mad(float a, float b, float c) {
    // separate mul+add rounding (matches numpy), blocks FMA contraction:
    // spike threshold is discontinuous.
    float t = a * b;
    asm volatile("" : "+v"(t));
    return t + c;
}

union HU4 { _Float16 h[4]; ushort4 u; };
union HU8 { _Float16 h[8]; uint4 u; };

// ---------------- Kernel 0: split fp32 -> fp16 hi/lo (x, Wq, Wk, Wv) + Wo fp16 ----------------
__global__ __launch_bounds__(256) void k_split(
    const float* __restrict__ x,
    const float* __restrict__ Wq, const float* __restrict__ Wk,
    const float* __restrict__ Wv, const float* __restrict__ Wo,
    _Float16* __restrict__ xh, _Float16* __restrict__ xl,
    _Float16* __restrict__ Wh, _Float16* __restrict__ Wl,
    _Float16* __restrict__ Woh)
{
    const int t = blockIdx.x * 256 + threadIdx.x;   // one float4 per thread
    float4 v;
    HU4 hi, lo;
    if (t < 262144) {
        v = ((const float4*)x)[t];
        hi.h[0] = (_Float16)v.x; lo.h[0] = (_Float16)(v.x - (float)hi.h[0]);
        hi.h[1] = (_Float16)v.y; lo.h[1] = (_Float16)(v.y - (float)hi.h[1]);
        hi.h[2] = (_Float16)v.z; lo.h[2] = (_Float16)(v.z - (float)hi.h[2]);
        hi.h[3] = (_Float16)v.w; lo.h[3] = (_Float16)(v.w - (float)hi.h[3]);
        ((ushort4*)xh)[t] = hi.u;
        ((ushort4*)xl)[t] = lo.u;
    } else {
        const int t2 = t - 262144;
        const int sel = t2 >> 16;          // 0..3 -> Wq, Wk, Wv, Wo
        const int o = t2 & 65535;
        const float* src = (sel == 0) ? Wq : ((sel == 1) ? Wk : ((sel == 2) ? Wv : Wo));
        v = ((const float4*)src)[o];
        hi.h[0] = (_Float16)v.x; lo.h[0] = (_Float16)(v.x - (float)hi.h[0]);
        hi.h[1] = (_Float16)v.y; lo.h[1] = (_Float16)(v.y - (float)hi.h[1]);
        hi.h[2] = (_Float16)v.z; lo.h[2] = (_Float16)(v.z - (float)hi.h[2]);
        hi.h[3] = (_Float16)v.w; lo.h[3] = (_Float16)(v.w - (float)hi.h[3]);
        if (sel < 3) {
            ((ushort4*)(Wh + sel * 262144))[o] = hi.u;
            ((ushort4*)(Wl + sel * 262144))[o] = lo.u;
        } else {
            ((ushort4*)Woh)[o] = hi.u;
        }
    }
}

// ---------------- Kernel 1: fused gate MLPs -> T_i ----------------
__global__ __launch_bounds__(256) void k_gates(
    const float* __restrict__ x,
    const float* __restrict__ gw1, const float* __restrict__ gb1,
    const float* __restrict__ gw2, const float* __restrict__ gb2,
    const float* __restrict__ gw3, const float* __restrict__ gb3,
    const float* __restrict__ cw1, const float* __restrict__ cb1,
    const float* __restrict__ cw2, const float* __restrict__ cb2,
    int* __restrict__ Ti, float* __restrict__ ti_out)
{
    __shared__ float xs[8][516];
    __shared__ float h1s[8][100];
    __shared__ float h2s[8][36];
    const int tok0 = blockIdx.x * 8;
    const int tid = threadIdx.x;

    for (int i = tid; i < 1024; i += 256) {
        int tok = i >> 7, c4 = i & 127;
        *(float4*)&xs[tok][c4 * 4] = ((const float4*)(x + (tok0 + tok) * 512))[c4];
    }
    __syncthreads();

    {
        const int o = tid & 127;
        const int tg = tid >> 7;
        const int oc = (o < 96) ? o : 95;
        const float4* wrow = (const float4*)((oc < 64) ? (gw1 + oc * 512) : (cw1 + (oc - 64) * 512));
        const float bias = (oc < 64) ? gb1[oc] : cb1[oc - 64];
        float acc[4];
#pragma unroll
        for (int t = 0; t < 4; t++) acc[t] = bias;
        for (int k4 = 0; k4 < 128; k4++) {
            float4 w4 = wrow[k4];
#pragma unroll
            for (int t = 0; t < 4; t++) {
                float4 x4 = *(const float4*)&xs[tg * 4 + t][k4 * 4];
                acc[t] = fmaf(w4.x, x4.x, acc[t]); acc[t] = fmaf(w4.y, x4.y, acc[t]);
                acc[t] = fmaf(w4.z, x4.z, acc[t]); acc[t] = fmaf(w4.w, x4.w, acc[t]);
            }
        }
        if (o < 96) {
#pragma unroll
            for (int t = 0; t < 4; t++) h1s[tg * 4 + t][o] = fmaxf(acc[t], 0.f);
        }
    }
    __syncthreads();
    {
        const int tok = tid >> 5, o2 = tid & 31;
        const float* w2 = gw2 + o2 * 64;
        float a = gb2[o2];
        for (int k = 0; k < 64; k++) a = fmaf(w2[k], h1s[tok][k], a);
        h2s[tok][o2] = fmaxf(a, 0.f);
    }
    __syncthreads();
    if (tid < 8) {
        const int tok = tid;
        float gg = gb3[0], cc = cb2[0];
        for (int k = 0; k < 32; k++) {
            gg = fmaf(gw3[k], h2s[tok][k], gg);
            cc = fmaf(cw2[k], h1s[tok][64 + k], cc);
        }
        float g = 1.f / (1.f + expf(-gg));
        float c = 1.f / (1.f + expf(-cc));
        float p1 = 0.7f * g, p2 = 0.3f * c;
        asm volatile("" : "+v"(p1), "+v"(p2));
        float comb = p1 + p2;
        float tf = ceilf(comb * 20.0f);
        tf = fminf(fmaxf(tf, 1.f), 20.f);
        Ti[tok0 + tok] = (int)tf;
        ti_out[tok0 + tok] = tf;
    }
}

// ---------------- Kernel 2: MFMA GEMM  Y = A @ B^T (+bias) ----------------
// NP=3: fp16x3 (hi/lo); NP=1: plain fp16. K=512 fixed, B is [NCAT][512], Y is [M][NCAT].
// BM=BN=64, BK=32, 256 thr = 4 waves, wave-tile 32x32. Grid (NCAT/64, M/64).
// MFMA 16x16x32_f16: A lane row=l&15, k=(l>>4)*8+j ; C/D col=l&15, row=(l>>4)*4+reg.
template<int NP, int NCAT>
__global__ __launch_bounds__(256) void k_gemm(
    const _Float16* __restrict__ Ah, const _Float16* __restrict__ Al,
    const _Float16* __restrict__ Bh, const _Float16* __restrict__ Bl,
    const float* __restrict__ bias,
    float* __restrict__ Y)
{
    __shared__ _Float16 AsH[4][64][8];
    __shared__ _Float16 BsH[4][64][8];
    __shared__ _Float16 AsL[(NP == 3) ? 4 : 1][64][8];
    __shared__ _Float16 BsL[(NP == 3) ? 4 : 1][64][8];

    const int bn = blockIdx.x * 64, bm = blockIdx.y * 64;
    const int tid = threadIdx.x, w = tid >> 6, l = tid & 63;
    const int mB = (w & 1) * 32, nB = (w >> 1) * 32;
    const int sr = tid >> 2, sk = tid & 3;    // staging: row 0..63, k-group 0..3
    const int fr = l & 15, fk = l >> 4;

    f32x4 acc[2][2] = {};

    uint4 pAh, pBh, pAl, pBl;
    pAh = *(const uint4*)(Ah + (bm + sr) * 512 + sk * 8);
    pBh = *(const uint4*)(Bh + (bn + sr) * 512 + sk * 8);
    if constexpr (NP == 3) {
        pAl = *(const uint4*)(Al + (bm + sr) * 512 + sk * 8);
        pBl = *(const uint4*)(Bl + (bn + sr) * 512 + sk * 8);
    }

    for (int k0 = 0; k0 < 512; k0 += 32) {
        __syncthreads();
        *(uint4*)&AsH[sk][sr][0] = pAh;
        *(uint4*)&BsH[sk][sr][0] = pBh;
        if constexpr (NP == 3) {
            *(uint4*)&AsL[sk][sr][0] = pAl;
            *(uint4*)&BsL[sk][sr][0] = pBl;
        }
        __syncthreads();
        const int kn = (k0 + 32) & 511;   // wraps harmlessly on last iter
        pAh = *(const uint4*)(Ah + (bm + sr) * 512 + kn + sk * 8);
        pBh = *(const uint4*)(Bh + (bn + sr) * 512 + kn + sk * 8);
        if constexpr (NP == 3) {
            pAl = *(const uint4*)(Al + (bm + sr) * 512 + kn + sk * 8);
            pBl = *(const uint4*)(Bl + (bn + sr) * 512 + kn + sk * 8);
        }

        f16x8 ah[2], al[2];
#pragma unroll
        for (int mt = 0; mt < 2; mt++) {
            ah[mt] = *(const f16x8*)&AsH[fk][mB + mt * 16 + fr][0];
            if constexpr (NP == 3) al[mt] = *(const f16x8*)&AsL[fk][mB + mt * 16 + fr][0];
        }
#pragma unroll
        for (int nt = 0; nt < 2; nt++) {
            f16x8 bh = *(const f16x8*)&BsH[fk][nB + nt * 16 + fr][0];
            if constexpr (NP == 3) {
                f16x8 bl = *(const f16x8*)&BsL[fk][nB + nt * 16 + fr][0];
#pragma unroll
                for (int mt = 0; mt < 2; mt++) {
                    acc[mt][nt] = __builtin_amdgcn_mfma_f32_16x16x32_f16(ah[mt], bh, acc[mt][nt], 0, 0, 0);
                    acc[mt][nt] = __builtin_amdgcn_mfma_f32_16x16x32_f16(ah[mt], bl, acc[mt][nt], 0, 0, 0);
                    acc[mt][nt] = __builtin_amdgcn_mfma_f32_16x16x32_f16(al[mt], bh, acc[mt][nt], 0, 0, 0);
                }
            } else {
#pragma unroll
                for (int mt = 0; mt < 2; mt++) {
                    acc[mt][nt] = __builtin_amdgcn_mfma_f32_16x16x32_f16(ah[mt], bh, acc[mt][nt], 0, 0, 0);
                }
            }
        }
    }

#pragma unroll
    for (int mt = 0; mt < 2; mt++) {
#pragma unroll
        for (int nt = 0; nt < 2; nt++) {
            const int j = bn + nB + nt * 16 + fr;
            float badd = (NP == 1) ? bias[j] : 0.f;
#pragma unroll
            for (int rr = 0; rr < 4; rr++) {
                const int i = bm + mB + mt * 16 + fk * 4 + rr;
                Y[i * NCAT + j] = acc[mt][nt][rr] + badd;
            }
        }
    }
}

// ---------------- Kernel 3: LIF + ballot bit-pack + v spike counts ----------------
__global__ __launch_bounds__(256) void k_lif(
    const float* __restrict__ qkv,           // [2048][1536]  (q|k|v per row)
    const int* __restrict__ Ti,
    const float* __restrict__ pAlpha, const float* __restrict__ pBeta,
    unsigned long long* __restrict__ qbits,  // [(b*8+h)*20 + t]*512 + s
    unsigned long long* __restrict__ kbits,
    _Float16* __restrict__ vmean)            // [tok*512 + h*64 + d] fp16
{
    const int wid = threadIdx.x >> 6, lane = threadIdx.x & 63;
    const int flat = blockIdx.x * 4 + wid;   // (b,s,h)
    const int tok = flat >> 3, h = flat & 7;
    const int b = tok >> 9, s = tok & 511;
    const float alpha = pAlpha[0], beta = pBeta[0];
    const int T = Ti[tok];
    const int off = tok * 1536 + h * 64 + lane;
    const float xq = qkv[off];
    const float xk = qkv[off + 512];
    const float xv = qkv[off + 1024];
    float iq = 0.f, vq = 0.f, ik = 0.f, vk = 0.f, iv = 0.f, vv = 0.f;
    int cnt = 0;
    const int base = ((b * 8 + h) * 20) * 512 + s;
#pragma unroll
    for (int t = 0; t < 20; t++) {
        iq = sep_mad(alpha, iq, xq); vq = sep_mad(beta, vq, iq);
        bool sq = vq >= 1.0f; vq = sq ? 0.f : vq;
        ik = sep_mad(alpha, ik, xk); vk = sep_mad(beta, vk, ik);
        bool sk = vk >= 1.0f; vk = sk ? 0.f : vk;
        iv = sep_mad(alpha, iv, xv); vv = sep_mad(beta, vv, iv);
        bool sv = vv >= 1.0f; vv = sv ? 0.f : vv;
        bool act = t < T;
        unsigned long long mq = __ballot(sq && act);
        unsigned long long mk = __ballot(sk && act);
        if (lane == 0) {
            qbits[base + t * 512] = mq;
            kbits[base + t * 512] = mk;
        }
        cnt += (sv && act) ? 1 : 0;
    }
    vmean[tok * 512 + h * 64 + lane] = (_Float16)((float)cnt / 20.0f);
}

// ---------------- Kernel 4: transpose v_mean [tok][h*64+d] -> vmT [bh][d][s] (fp16) ----------------
__global__ __launch_bounds__(256) void k_pack(
    const _Float16* __restrict__ vmean, _Float16* __restrict__ vmT)
{
    __shared__ _Float16 T[64][72];
    const int s0 = blockIdx.x * 64;
    const int bh = blockIdx.y;
    const int b = bh >> 3, h = bh & 7;
    const int t = threadIdx.x;
    const int si = t >> 2;
#pragma unroll
    for (int it = 0; it < 2; it++) {
        const int dv = (t & 3) + it * 4;
        uint4 v = *(const uint4*)(vmean + (b * 512 + s0 + si) * 512 + h * 64 + dv * 8);
        *(uint4*)&T[si][dv * 8] = v;
    }
    __syncthreads();
    const int sv = t & 63;
#pragma unroll
    for (int it = 0; it < 16; it++) {
        const int d = it * 4 + (t >> 6);
        vmT[(bh * 64 + d) * 512 + s0 + sv] = T[sv][d];
    }
}

// ---------------- Kernel 5: popcount scores + softmax -> attn (+fused reg) ----------------
__global__ __launch_bounds__(256) void k_scores(
    const unsigned long long* __restrict__ qbits,
    const unsigned long long* __restrict__ kbits,
    float* __restrict__ attn,
    const int* __restrict__ Ti, float* __restrict__ regp)
{
    const int bh = blockIdx.x >> 5;            // 0..31
    const int i0 = (blockIdx.x & 31) * 16;
    const int base = bh * 20 * 512;
    __shared__ unsigned long long qs[20][16];
    __shared__ float sc[16][512];
    const int tid = threadIdx.x;
    for (int idx = tid; idx < 320; idx += 256) {
        int t = idx >> 4, r = idx & 15;
        qs[t][r] = qbits[base + t * 512 + i0 + r];
    }
    __syncthreads();

    {
        const unsigned long long* kbp = kbits + base + tid;
        int acc0[16] = {}, acc1[16] = {};
#pragma unroll
        for (int tc = 0; tc < 4; tc++) {
            unsigned long long kv0[5], kv1[5];
#pragma unroll
            for (int t = 0; t < 5; t++) {
                kv0[t] = kbp[(tc * 5 + t) * 512];
                kv1[t] = kbp[(tc * 5 + t) * 512 + 256];
            }
#pragma unroll
            for (int r = 0; r < 16; r++) {
#pragma unroll
                for (int t = 0; t < 5; t++) {
                    unsigned long long qv = qs[tc * 5 + t][r];
                    acc0[r] += __popcll(qv & kv0[t]);
                    acc1[r] += __popcll(qv & kv1[t]);
                }
            }
        }
#pragma unroll
        for (int r = 0; r < 16; r++) {
            sc[r][tid] = (float)acc0[r] * 0.125f;
            sc[r][tid + 256] = (float)acc1[r] * 0.125f;
        }
    }
    __syncthreads();

    const int wid = tid >> 6, lane = tid & 63;
#pragma unroll
    for (int rr = 0; rr < 4; rr++) {
        const int r = wid * 4 + rr;
        float vals[8];
        float m = -1e30f;
#pragma unroll
        for (int k = 0; k < 8; k++) { vals[k] = sc[r][lane + 64 * k]; m = fmaxf(m, vals[k]); }
#pragma unroll
        for (int off = 32; off; off >>= 1) m = fmaxf(m, __shfl_xor(m, off));
        float sum = 0.f;
#pragma unroll
        for (int k = 0; k < 8; k++) { vals[k] = expf(vals[k] - m); sum += vals[k]; }
#pragma unroll
        for (int off = 32; off; off >>= 1) sum += __shfl_xor(sum, off);
        float* arow = attn + ((long)bh * 512 + (i0 + r)) * 512;
#pragma unroll
        for (int k = 0; k < 8; k++) arow[lane + 64 * k] = vals[k] / sum;
    }

    if (blockIdx.x == 0 && tid < 64) {
        int s = 0;
        for (int k = tid; k < 2048; k += 64) s += Ti[k];
#pragma unroll
        for (int off = 32; off; off >>= 1) s += __shfl_xor(s, off);
        if (tid == 0) regp[0] = 1e-3f * ((float)s / 2048.0f);
    }
}

// ---------------- Kernel 6: MFMA AV  hout = attn @ v_mean  (per b,h; fp16) ----------------
// BM=64 (i), BN=64 (d), BK=32 (j), K=512. grid (8, 32). 4 waves, wave-tile 32x32.
__global__ __launch_bounds__(256) void k_av(
    const float* __restrict__ attn,
    const _Float16* __restrict__ vmT,   // [bh][d][s]
    _Float16* __restrict__ hout)        // [tok][h*64+d] fp16
{
    __shared__ _Float16 Aa[4][64][8];
    __shared__ _Float16 Bb[4][64][8];
    const int i0 = blockIdx.x * 64;
    const int bh = blockIdx.y;
    const int b = bh >> 3, h = bh & 7;
    const int tid = threadIdx.x, w = tid >> 6, l = tid & 63;
    const int mB = (w & 1) * 32, nB = (w >> 1) * 32;
    const int sr = tid >> 2, sk = tid & 3;
    const int fr = l & 15, fk = l >> 4;
    const float* abase = attn + ((long)bh * 512 + i0) * 512;
    const _Float16* bbase = vmT + bh * 64 * 512;

    f32x4 acc[2][2] = {};

    float4 pa0 = *(const float4*)(abase + sr * 512 + sk * 8);
    float4 pa1 = *(const float4*)(abase + sr * 512 + sk * 8 + 4);
    uint4 pb = *(const uint4*)(bbase + sr * 512 + sk * 8);

    for (int k0 = 0; k0 < 512; k0 += 32) {
        __syncthreads();
        {
            HU8 z;
            z.h[0] = (_Float16)pa0.x; z.h[1] = (_Float16)pa0.y;
            z.h[2] = (_Float16)pa0.z; z.h[3] = (_Float16)pa0.w;
            z.h[4] = (_Float16)pa1.x; z.h[5] = (_Float16)pa1.y;
            z.h[6] = (_Float16)pa1.z; z.h[7] = (_Float16)pa1.w;
            *(uint4*)&Aa[sk][sr][0] = z.u;
            *(uint4*)&Bb[sk][sr][0] = pb;
        }
        __syncthreads();
        const int kn = (k0 + 32) & 511;
        pa0 = *(const float4*)(abase + sr * 512 + kn + sk * 8);
        pa1 = *(const float4*)(abase + sr * 512 + kn + sk * 8 + 4);
        pb = *(const uint4*)(bbase + sr * 512 + kn + sk * 8);

        f16x8 ah[2];
#pragma unroll
        for (int mt = 0; mt < 2; mt++)
            ah[mt] = *(const f16x8*)&Aa[fk][mB + mt * 16 + fr][0];
#pragma unroll
        for (int nt = 0; nt < 2; nt++) {
            f16x8 bv = *(const f16x8*)&Bb[fk][nB + nt * 16 + fr][0];
#pragma unroll
            for (int mt = 0; mt < 2; mt++)
                acc[mt][nt] = __builtin_amdgcn_mfma_f32_16x16x32_f16(ah[mt], bv, acc[mt][nt], 0, 0, 0);
        }
    }

#pragma unroll
    for (int mt = 0; mt < 2; mt++) {
#pragma unroll
        for (int nt = 0; nt < 2; nt++) {
            const int d = nB + nt * 16 + fr;
#pragma unroll
            for (int rr = 0; rr < 4; rr++) {
                const int i = i0 + mB + mt * 16 + fk * 4 + rr;
                hout[(b * 512 + i) * 512 + h * 64 + d] = (_Float16)acc[mt][nt][rr];
            }
        }
    }
}

extern "C" void kernel_launch(void* const* d_in, const int* in_sizes, int n_in,
                              void* d_out, int out_size, void* d_ws, size_t ws_size,
                              hipStream_t stream)
{
    const float* x    = (const float*)d_in[0];
    const float* Wq   = (const float*)d_in[1];
    const float* Wk   = (const float*)d_in[2];
    const float* Wv   = (const float*)d_in[3];
    const float* Wo   = (const float*)d_in[4];
    const float* bo   = (const float*)d_in[5];
    const float* gw1  = (const float*)d_in[6];
    const float* gb1  = (const float*)d_in[7];
    const float* gw2  = (const float*)d_in[8];
    const float* gb2  = (const float*)d_in[9];
    const float* gw3  = (const float*)d_in[10];
    const float* gb3  = (const float*)d_in[11];
    const float* cw1  = (const float*)d_in[12];
    const float* cb1  = (const float*)d_in[13];
    const float* cw2  = (const float*)d_in[14];
    const float* cb2  = (const float*)d_in[15];
    const float* alpha = (const float*)d_in[16];
    const float* beta  = (const float*)d_in[17];

    float* out   = (float*)d_out;                 // [2048*512]
    float* attn  = out + 1048576;                 // [32][512][512]
    float* regp  = out + 1048576 + 8388608;
    float* tiout = regp + 1;

    // workspace (21.5 MiB, dead-region aliasing):
    //   qkv fp32 [0, 12582912)  (dead after k_lif):
    //       vmT    at 0         (2 MiB)
    //       hout_h at 2097152   (2 MiB)
    //   vmean_h 12582912 | Ti 14680064 | xh 14688256 | xl 16785408
    //   Wh 18882560 | Wl 20455424 | Wo_h 22028288
    //   qb aliases xh region (written by k_lif, after gemm consumed xh/xl)
    char* ws = (char*)d_ws;
    float*    qkv    = (float*)ws;                      // [2048][1536]
    _Float16* vmT    = (_Float16*)ws;
    _Float16* hout_h = (_Float16*)(ws + 2097152);
    _Float16* vmean_h= (_Float16*)(ws + 12582912);
    int*      Ti     = (int*)(ws + 14680064);
    _Float16* xh     = (_Float16*)(ws + 14688256);
    _Float16* xl     = (_Float16*)(ws + 16785408);
    _Float16* Wh     = (_Float16*)(ws + 18882560);      // [1536][512] = Wq|Wk|Wv
    _Float16* Wl     = (_Float16*)(ws + 20455424);
    _Float16* Woh    = (_Float16*)(ws + 22028288);
    unsigned long long* qb = (unsigned long long*)(ws + 14688256);
    unsigned long long* kb = (unsigned long long*)(ws + 17309696);

    k_split<<<2048, 256, 0, stream>>>(x, Wq, Wk, Wv, Wo, xh, xl, Wh, Wl, Woh);
    k_gates<<<256, 256, 0, stream>>>(x, gw1, gb1, gw2, gb2, gw3, gb3,
                                     cw1, cb1, cw2, cb2, Ti, tiout);
    k_gemm<3, 1536><<<dim3(24, 32), 256, 0, stream>>>(xh, xl, Wh, Wl, nullptr, qkv);
    k_lif<<<4096, 256, 0, stream>>>(qkv, Ti, alpha, beta, qb, kb, vmean_h);
    k_pack<<<dim3(8, 32), 256, 0, stream>>>(vmean_h, vmT);
    k_scores<<<1024, 256, 0, stream>>>(qb, kb, attn, Ti, regp);
    k_av<<<dim3(8, 32), 256, 0, stream>>>(attn, vmT, hout_h);
    k_gemm<1, 512><<<dim3(8, 32), 256, 0, stream>>>(hout_h, nullptr, Woh, nullptr, bo, out);
}